// Round 1
// 2352.506 us; speedup vs baseline: 1.0408x; 1.0408x over previous
//
#include <hip/hip_runtime.h>

#define CDIV(a, b) (((a) + (b) - 1) / (b))

// ---------------------------------------------------------------------------
// Tiled conv 3x3 pad 1 stride {1,2} + bias + PReLU.
// 256 threads -> TSxTS output tile, KO=8 output channels in registers,
// each thread computes (TS/16)^2 pixels. Input plane staged per-ci in LDS.
// ---------------------------------------------------------------------------
template <int STRIDE, int TS>
__global__ __launch_bounds__(256)
void conv3x3_tile_kernel(const float* __restrict__ in,
                         const float* __restrict__ wgt,
                         const float* __restrict__ bias,
                         const float* __restrict__ alpha,
                         float* __restrict__ out,
                         int Ci, int Hi, int Wi, int Co, int Ho, int Wo,
                         int nTX) {
    constexpr int PB = TS / 16;               // pixels per thread per dim
    constexpr int IS = TS * STRIDE + 2;       // input tile side
    constexpr int KO = 8;
    constexpr int SP = (PB - 1) * STRIDE + 3; // per-thread tap span
    __shared__ float s_in[IS * IS];
    __shared__ float s_w[KO * 12];

    const int b   = blockIdx.z;
    const int co0 = blockIdx.y * KO;
    const int tX  = (blockIdx.x % nTX) * TS;
    const int tY  = (blockIdx.x / nTX) * TS;
    const int t   = threadIdx.x;
    const int tcx = t & 15, tcy = t >> 4;
    const int ox0 = PB * tcx, oy0 = PB * tcy;

    float acc[KO][PB][PB];
#pragma unroll
    for (int ko = 0; ko < KO; ++ko)
#pragma unroll
        for (int dy = 0; dy < PB; ++dy)
#pragma unroll
            for (int dx = 0; dx < PB; ++dx) acc[ko][dy][dx] = 0.f;

    const float* inb = in + (size_t)b * Ci * Hi * Wi;
    const int ix0 = tX * STRIDE - 1, iy0 = tY * STRIDE - 1;

    for (int ci = 0; ci < Ci; ++ci) {
        __syncthreads();
        const float* inp = inb + (size_t)ci * Hi * Wi;
        for (int i = t; i < IS * IS; i += 256) {
            const int r = i / IS, c = i - r * IS;
            const int gy = iy0 + r, gx = ix0 + c;
            float v = 0.f;
            if (gy >= 0 && gy < Hi && gx >= 0 && gx < Wi)
                v = inp[(size_t)gy * Wi + gx];
            s_in[i] = v;
        }
        if (t < KO * 9) {
            const int ko = t / 9, k = t - ko * 9;
            s_w[ko * 12 + k] = wgt[((size_t)(co0 + ko) * Ci + ci) * 9 + k];
        }
        __syncthreads();

        float tap[SP][SP];
#pragma unroll
        for (int r = 0; r < SP; ++r)
#pragma unroll
            for (int c = 0; c < SP; ++c)
                tap[r][c] = s_in[(oy0 * STRIDE + r) * IS + ox0 * STRIDE + c];

#pragma unroll
        for (int ko = 0; ko < KO; ++ko) {
            float w[9];
#pragma unroll
            for (int k = 0; k < 9; ++k) w[k] = s_w[ko * 12 + k];
#pragma unroll
            for (int dy = 0; dy < PB; ++dy)
#pragma unroll
                for (int dx = 0; dx < PB; ++dx) {
                    float a = acc[ko][dy][dx];
#pragma unroll
                    for (int ky = 0; ky < 3; ++ky)
#pragma unroll
                        for (int kx = 0; kx < 3; ++kx)
                            a += tap[dy * STRIDE + ky][dx * STRIDE + kx] *
                                 w[ky * 3 + kx];
                    acc[ko][dy][dx] = a;
                }
        }
    }

#pragma unroll
    for (int ko = 0; ko < KO; ++ko) {
        const int co = co0 + ko;
        const float bv = bias[co], av = alpha[co];
#pragma unroll
        for (int dy = 0; dy < PB; ++dy) {
            const int oy = tY + oy0 + dy;
#pragma unroll
            for (int dx = 0; dx < PB; ++dx) {
                const int ox = tX + ox0 + dx;
                float v = acc[ko][dy][dx] + bv;
                v = v >= 0.f ? v : av * v;
                out[(((size_t)b * Co + co) * Ho + oy) * Wo + ox] = v;
            }
        }
    }
}

// ---------------------------------------------------------------------------
// flow halving: 2x2 mean * 0.5 == sum * 0.125
// ---------------------------------------------------------------------------
__global__ void halve_flow_kernel(const float* __restrict__ in,
                                  float* __restrict__ out,
                                  int BC, int Ho, int Wo, int Hi, int Wi) {
    const int idx = blockIdx.x * blockDim.x + threadIdx.x;
    const int total = BC * Ho * Wo;
    if (idx >= total) return;
    const int wo = idx % Wo;
    int t = idx / Wo;
    const int ho = t % Ho;
    const int bc = t / Ho;
    const float* p = in + ((size_t)bc * Hi + 2 * ho) * Wi + 2 * wo;
    out[idx] = (p[0] + p[1] + p[Wi] + p[Wi + 1]) * 0.125f;
}

// ---------------------------------------------------------------------------
// Outlier splat pre-pass: sources with |flow| > thr (statistically ~never for
// this input) are splatted with device atomics into the num/cnt overlay.
// Sets *flag so the owner-tile kernel knows to read the overlay.
// thr MUST equal (float)(RP-1) of the matching owner kernel.
// ---------------------------------------------------------------------------
__global__ void splat_outlier_kernel(const float* __restrict__ feat,
                                     const float* __restrict__ flow,
                                     float* __restrict__ num,
                                     float* __restrict__ cnt,
                                     int* __restrict__ flag,
                                     int B, int C, int H, int W, float thr) {
    const int HW = H * W;
    const int idx = blockIdx.x * blockDim.x + threadIdx.x;
    if (idx >= B * HW) return;
    const int b = idx / HW, px = idx - b * HW;
    const int y = px / W, x = px - y * W;
    const float dx = flow[(size_t)b * 2 * HW + px];
    const float dy = flow[(size_t)b * 2 * HW + HW + px];
    if (fabsf(dx) <= thr && fabsf(dy) <= thr) return;   // fast-path source
    atomicAdd(flag, 1);
    const float fx = dx + (float)x, fy = dy + (float)y;
    const float x0f = floorf(fx), y0f = floorf(fy);
    const int x0 = (int)x0f, y0 = (int)y0f;
    const float ax = fx - x0f, ay = fy - y0f;
    const float w[4] = {(1.f - ax) * (1.f - ay), ax * (1.f - ay),
                        (1.f - ax) * ay,         ax * ay};
    const int cx[4] = {x0, x0 + 1, x0, x0 + 1};
    const int cy[4] = {y0, y0, y0 + 1, y0 + 1};
    float* cb = cnt + (size_t)b * HW;
    for (int k = 0; k < 4; ++k) {
        if (cx[k] < 0 || cx[k] >= W || cy[k] < 0 || cy[k] >= H) continue;
        if (w[k] == 0.f) continue;
        const size_t d = (size_t)cy[k] * W + cx[k];
        atomicAdd(cb + d, w[k]);
        for (int c = 0; c < C; ++c)
            atomicAdd(num + ((size_t)b * C + c) * HW + d,
                      feat[((size_t)b * C + c) * HW + px] * w[k]);
    }
}

// ---------------------------------------------------------------------------
// Owner-tile splat: each block exclusively owns a TS x TS destination tile.
// It scans the source window [t0-RP, t0+TS+RP), accumulates the bilinear
// corners that land in its interior into LDS (feat channels + cnt), then
// divides and writes the final average with PLAIN coalesced stores.
// No global atomics on the fast path. Sources with |flow| > RP-1 are skipped
// here (handled exactly by splat_outlier_kernel; overlay is added iff *oflag).
// ---------------------------------------------------------------------------
template <int TS, int RP, int NCH>
__global__ __launch_bounds__(256)
void splat_owner_kernel(const float* __restrict__ feat,
                        const float* __restrict__ flow,
                        const float* __restrict__ cnt_ov,
                        const int* __restrict__ oflag,
                        float* __restrict__ out,
                        int C, int H, int W, int nTX) {
    constexpr int WS = TS + 2 * RP;     // source window side
    constexpr int NSRC = WS * WS;
    constexpr float THR = (float)(RP - 1);
    __shared__ float s_num[NCH][TS * TS];
    __shared__ float s_cnt[TS * TS];

    const int b   = blockIdx.z;
    const int c0  = blockIdx.y * NCH;
    const int tx0 = (blockIdx.x % nTX) * TS;
    const int ty0 = (blockIdx.x / nTX) * TS;
    const int t   = threadIdx.x;
    const int HW  = H * W;
    const float* flx = flow + (size_t)b * 2 * HW;
    const float* fly = flx + HW;
    const float* fb  = feat + ((size_t)b * C + c0) * HW;

    for (int i = t; i < TS * TS; i += 256) {
        s_cnt[i] = 0.f;
#pragma unroll
        for (int ch = 0; ch < NCH; ++ch) s_num[ch][i] = 0.f;
    }
    __syncthreads();

    for (int sp = t; sp < NSRC; sp += 256) {
        const int wy = sp / WS, wx = sp - wy * WS;
        const int y = ty0 - RP + wy, x = tx0 - RP + wx;
        if (y < 0 || y >= H || x < 0 || x >= W) continue;
        const float dx = flx[(size_t)y * W + x];
        const float dy = fly[(size_t)y * W + x];
        if (fabsf(dx) > THR || fabsf(dy) > THR) continue;  // outlier pre-pass
        const float fx = dx + (float)x, fy = dy + (float)y;
        const float x0f = floorf(fx), y0f = floorf(fy);
        const int x0 = (int)x0f, y0 = (int)y0f;
        const float ax = fx - x0f, ay = fy - y0f;
        const float w00 = (1.f - ax) * (1.f - ay);
        const float w10 = ax * (1.f - ay);
        const float w01 = (1.f - ax) * ay;
        const float w11 = ax * ay;
        // interior ownership (interior cells are in-image by construction)
        const int lx0 = x0 - tx0, ly0 = y0 - ty0;
        const bool inx0 = (lx0 >= 0) & (lx0 < TS);
        const bool inx1 = (lx0 + 1 >= 0) & (lx0 + 1 < TS);
        const bool iny0 = (ly0 >= 0) & (ly0 < TS);
        const bool iny1 = (ly0 + 1 >= 0) & (ly0 + 1 < TS);
        const bool in00 = inx0 & iny0, in10 = inx1 & iny0;
        const bool in01 = inx0 & iny1, in11 = inx1 & iny1;
        if (!(in00 | in10 | in01 | in11)) continue;

        float f[NCH];
        const float* fp = fb + (size_t)y * W + x;
#pragma unroll
        for (int ch = 0; ch < NCH; ++ch) f[ch] = fp[(size_t)ch * HW];

        const int cell = ly0 * TS + lx0;
        if (in00) {
            atomicAdd(&s_cnt[cell], w00);
#pragma unroll
            for (int ch = 0; ch < NCH; ++ch)
                atomicAdd(&s_num[ch][cell], f[ch] * w00);
        }
        if (in10) {
            atomicAdd(&s_cnt[cell + 1], w10);
#pragma unroll
            for (int ch = 0; ch < NCH; ++ch)
                atomicAdd(&s_num[ch][cell + 1], f[ch] * w10);
        }
        if (in01) {
            atomicAdd(&s_cnt[cell + TS], w01);
#pragma unroll
            for (int ch = 0; ch < NCH; ++ch)
                atomicAdd(&s_num[ch][cell + TS], f[ch] * w01);
        }
        if (in11) {
            atomicAdd(&s_cnt[cell + TS + 1], w11);
#pragma unroll
            for (int ch = 0; ch < NCH; ++ch)
                atomicAdd(&s_num[ch][cell + TS + 1], f[ch] * w11);
        }
    }
    __syncthreads();

    const int has = *oflag;   // uniform: overlay only if outliers existed
    for (int i = t; i < TS * TS; i += 256) {
        const int ly = i / TS, lx = i - ly * TS;
        const size_t px = (size_t)(ty0 + ly) * W + (tx0 + lx);
        float cv = s_cnt[i];
        if (has) cv += cnt_ov[(size_t)b * HW + px];
        const float denom = (cv == 0.f) ? 1.f : cv;
        const float inv = 1.f / denom;
#pragma unroll
        for (int ch = 0; ch < NCH; ++ch) {
            float v = s_num[ch][i];
            const size_t go = ((size_t)b * C + c0 + ch) * HW + px;
            if (has) v += out[go];
            out[go] = v * inv;
        }
    }
}

extern "C" void kernel_launch(void* const* d_in, const int* in_sizes, int n_in,
                              void* d_out, int out_size, void* d_ws, size_t ws_size,
                              hipStream_t stream) {
    (void)in_sizes; (void)n_in; (void)ws_size;

    const float* img  = (const float*)d_in[0];
    const float* flow = (const float*)d_in[1];
    const float* P[4][6];
    for (int i = 0; i < 4; ++i)
        for (int j = 0; j < 6; ++j)
            P[i][j] = (const float*)d_in[2 + 6 * i + j];

    const int Bn = 16;
    float* ws = (float*)d_ws;
    float* bufA = ws;                       // 16M floats
    float* bufB = ws + 16777216;            // 16M floats
    float* flA  = ws + 33554432;            // 2M floats
    float* flB  = ws + 35651584;            // 512K floats
    float* cnt  = ws + 36175872;            // 1M floats (outlier cnt overlay)
    int*   flag = (int*)(ws + 37224448);    // outlier-present flag
    float* out  = (float*)d_out;

    hipMemsetAsync(d_out, 0, (size_t)out_size * sizeof(float), stream);

    auto conv = [&](const float* in, const float* w, const float* b,
                    const float* a, float* o, int Ci, int Hi, int Wi,
                    int Co, int stride) {
        const int Ho = Hi / stride, Wo = Wi / stride;
        const int TS = (Wo >= 128) ? 32 : 16;
        const int nTX = Wo / TS, nTY = Ho / TS;
        dim3 grid(nTX * nTY, Co / 8, Bn);
        if (stride == 1) {
            if (TS == 32)
                hipLaunchKernelGGL((conv3x3_tile_kernel<1, 32>), grid, dim3(256), 0,
                                   stream, in, w, b, a, o, Ci, Hi, Wi, Co, Ho, Wo, nTX);
            else
                hipLaunchKernelGGL((conv3x3_tile_kernel<1, 16>), grid, dim3(256), 0,
                                   stream, in, w, b, a, o, Ci, Hi, Wi, Co, Ho, Wo, nTX);
        } else {
            if (TS == 32)
                hipLaunchKernelGGL((conv3x3_tile_kernel<2, 32>), grid, dim3(256), 0,
                                   stream, in, w, b, a, o, Ci, Hi, Wi, Co, Ho, Wo, nTX);
            else
                hipLaunchKernelGGL((conv3x3_tile_kernel<2, 16>), grid, dim3(256), 0,
                                   stream, in, w, b, a, o, Ci, Hi, Wi, Co, Ho, Wo, nTX);
        }
    };
    auto halve = [&](const float* in, float* o, int Hi, int Wi) {
        const int Ho = Hi / 2, Wo = Wi / 2;
        const int total = Bn * 2 * Ho * Wo;
        hipLaunchKernelGGL(halve_flow_kernel, dim3(CDIV(total, 256)), dim3(256),
                           0, stream, in, o, Bn * 2, Ho, Wo, Hi, Wi);
    };

    float* p1 = out;
    float* p2 = p1 + (size_t)Bn * 16 * 256 * 256;
    float* p3 = p2 + (size_t)Bn * 32 * 128 * 128;
    float* p4 = p3 + (size_t)Bn * 64 * 64 * 64;

    // ---- level 1
    conv(img,  P[0][0], P[0][1], P[0][2], bufA, 3, 512, 512, 16, 2);
    conv(bufA, P[0][3], P[0][4], P[0][5], bufB, 16, 256, 256, 16, 1);
    halve(flow, flA, 512, 512);
    {
        const int C = 16, H = 256, W = 256;
        hipMemsetAsync(cnt, 0, (size_t)Bn * H * W * sizeof(float), stream);
        hipMemsetAsync(flag, 0, sizeof(int), stream);
        hipLaunchKernelGGL(splat_outlier_kernel, dim3(CDIV(Bn * H * W, 256)),
                           dim3(256), 0, stream, bufB, flA, p1, cnt, flag,
                           Bn, C, H, W, 7.f);
        hipLaunchKernelGGL((splat_owner_kernel<32, 8, 8>),
                           dim3((W / 32) * (H / 32), C / 8, Bn), dim3(256), 0,
                           stream, bufB, flA, cnt, flag, p1, C, H, W, W / 32);
    }

    // ---- level 2
    conv(bufB, P[1][0], P[1][1], P[1][2], bufA, 16, 256, 256, 32, 2);
    conv(bufA, P[1][3], P[1][4], P[1][5], bufB, 32, 128, 128, 32, 1);
    halve(flA, flB, 256, 256);
    {
        const int C = 32, H = 128, W = 128;
        hipMemsetAsync(cnt, 0, (size_t)Bn * H * W * sizeof(float), stream);
        hipMemsetAsync(flag, 0, sizeof(int), stream);
        hipLaunchKernelGGL(splat_outlier_kernel, dim3(CDIV(Bn * H * W, 256)),
                           dim3(256), 0, stream, bufB, flB, p2, cnt, flag,
                           Bn, C, H, W, 3.f);
        hipLaunchKernelGGL((splat_owner_kernel<32, 4, 8>),
                           dim3((W / 32) * (H / 32), C / 8, Bn), dim3(256), 0,
                           stream, bufB, flB, cnt, flag, p2, C, H, W, W / 32);
    }

    // ---- level 3
    conv(bufB, P[2][0], P[2][1], P[2][2], bufA, 32, 128, 128, 64, 2);
    conv(bufA, P[2][3], P[2][4], P[2][5], bufB, 64, 64, 64, 64, 1);
    halve(flB, flA, 128, 128);
    {
        const int C = 64, H = 64, W = 64;
        hipMemsetAsync(cnt, 0, (size_t)Bn * H * W * sizeof(float), stream);
        hipMemsetAsync(flag, 0, sizeof(int), stream);
        hipLaunchKernelGGL(splat_outlier_kernel, dim3(CDIV(Bn * H * W, 256)),
                           dim3(256), 0, stream, bufB, flA, p3, cnt, flag,
                           Bn, C, H, W, 2.f);
        hipLaunchKernelGGL((splat_owner_kernel<16, 3, 16>),
                           dim3((W / 16) * (H / 16), C / 16, Bn), dim3(256), 0,
                           stream, bufB, flA, cnt, flag, p3, C, H, W, W / 16);
    }

    // ---- level 4
    conv(bufB, P[3][0], P[3][1], P[3][2], bufA, 64, 64, 64, 128, 2);
    conv(bufA, P[3][3], P[3][4], P[3][5], bufB, 128, 32, 32, 128, 1);
    halve(flA, flB, 64, 64);
    {
        const int C = 128, H = 32, W = 32;
        hipMemsetAsync(cnt, 0, (size_t)Bn * H * W * sizeof(float), stream);
        hipMemsetAsync(flag, 0, sizeof(int), stream);
        hipLaunchKernelGGL(splat_outlier_kernel, dim3(CDIV(Bn * H * W, 256)),
                           dim3(256), 0, stream, bufB, flB, p4, cnt, flag,
                           Bn, C, H, W, 1.f);
        hipLaunchKernelGGL((splat_owner_kernel<16, 2, 16>),
                           dim3((W / 16) * (H / 16), C / 16, Bn), dim3(256), 0,
                           stream, bufB, flB, cnt, flag, p4, C, H, W, W / 16);
    }
}